// Round 1
// 310.048 us; speedup vs baseline: 1.1191x; 1.1191x over previous
//
#include <hip/hip_runtime.h>

#define D 1024
#define NB1 48
#define NB2 48
#define RR 36
#define LL 30
#define NH 4

typedef short bf16x8 __attribute__((ext_vector_type(8)));
typedef float f32x4 __attribute__((ext_vector_type(4)));
typedef float f32x2 __attribute__((ext_vector_type(2)));
typedef unsigned short u16x8 __attribute__((ext_vector_type(8)));

#define MFMA16(a, b, c) __builtin_amdgcn_mfma_f32_16x16x32_bf16(a, b, c, 0, 0, 0)

__device__ __forceinline__ unsigned short f2bf(float x) {
  unsigned u = __float_as_uint(x);
  u += 0x7FFF + ((u >> 16) & 1);
  return (unsigned short)(u >> 16);
}
__device__ __forceinline__ float bf2f(unsigned short h) {
  return __uint_as_float(((unsigned)h) << 16);
}
__device__ __forceinline__ void split8(const float* v, bf16x8& h8, bf16x8& l8) {
  u16x8 hi, lo;
#pragma unroll
  for (int i = 0; i < 8; ++i) {
    unsigned short h = f2bf(v[i]);
    hi[i] = h;
    lo[i] = f2bf(v[i] - bf2f(h));
  }
  h8 = __builtin_bit_cast(bf16x8, hi);
  l8 = __builtin_bit_cast(bf16x8, lo);
}
__device__ __forceinline__ f32x2 shflx2(f32x2 v, int m) {
  double d = __builtin_bit_cast(double, v);
  d = __shfl_xor(d, m);
  return __builtin_bit_cast(f32x2, d);
}

// ---- fp32 row-major (rows x 1024) -> split-bf16 MFMA fragment layout ----
__device__ __forceinline__ void conv_body(const float* __restrict__ X,
                                          unsigned short* __restrict__ out,
                                          int rows, int g) {
  const int lane = threadIdx.x & 63;
  const int tile = g >> 5, kc = g & 31;
  const int row = tile * 16 + (lane & 15);
  const int k = kc * 32 + (lane >> 4) * 8;
  float v[8];
  if (row < rows) {
    const float4* s = (const float4*)(X + (size_t)row * 1024 + k);
    float4 x0 = s[0], x1 = s[1];
    v[0] = x0.x; v[1] = x0.y; v[2] = x0.z; v[3] = x0.w;
    v[4] = x1.x; v[5] = x1.y; v[6] = x1.z; v[7] = x1.w;
  } else {
#pragma unroll
    for (int i = 0; i < 8; ++i) v[i] = 0.f;
  }
  bf16x8 hi, lo;
  split8(v, hi, lo);
  bf16x8* o = (bf16x8*)(out + (size_t)g * 1024 + lane * 8);
  o[0] = hi;
  o[64] = lo;
}

// 6 input matrices in one launch. grid (864, 6)
__global__ __launch_bounds__(256) void conv6(
    const float* __restrict__ v1, const float* __restrict__ v2,
    const float* __restrict__ wimg, const float* __restrict__ wtxt,
    const float* __restrict__ w1a, const float* __restrict__ w1b,
    unsigned short* v1f, unsigned short* v2f, unsigned short* wimgf,
    unsigned short* wtxtf, unsigned short* w1af, unsigned short* w1bf) {
  const float* X; unsigned short* O; int rows;
  switch (blockIdx.y) {
    case 0: X = v1; O = v1f; rows = 1728; break;
    case 1: X = v2; O = v2f; rows = 1440; break;
    case 2: X = wimg; O = wimgf; rows = 1024; break;
    case 3: X = wtxt; O = wtxtf; rows = 1024; break;
    case 4: X = w1a; O = w1af; rows = 1024; break;
    default: X = w1b; O = w1bf; rows = 1024; break;
  }
  const int tiles = (rows + 15) >> 4;
  const int g = blockIdx.x * 4 + (threadIdx.x >> 6);
  if (g >= tiles * 32) return;
  conv_body(X, O, rows, g);
}

// k1 (1728) / k2 (1440). grid (864, 2)
__global__ __launch_bounds__(256) void conv_k(const float* __restrict__ k1,
                                              const float* __restrict__ k2,
                                              unsigned short* k1f, unsigned short* k2f) {
  const float* X = blockIdx.y ? k2 : k1;
  unsigned short* O = blockIdx.y ? k2f : k1f;
  const int rows = blockIdx.y ? 1440 : 1728;
  const int tiles = (rows + 15) >> 4;
  const int g = blockIdx.x * 4 + (threadIdx.x >> 6);
  if (g >= tiles * 32) return;
  conv_body(X, O, rows, g);
}

// G2a -> B-frag [b][nt(64)][part(2)][512] ; G1b -> [a][nt(64)][kc(2)][part(2)][512]
// grid (768, 2). Also transposes w2a/w2b to float4-per-col (blocks x<4, y==0).
__global__ __launch_bounds__(256) void convG(const float* __restrict__ G2a,
                                             const float* __restrict__ G1b,
                                             const float* __restrict__ w2a,
                                             const float* __restrict__ w2b,
                                             unsigned short* G2aF, unsigned short* G1bF,
                                             float4* __restrict__ w2at,
                                             float4* __restrict__ w2bt) {
  const int t = threadIdx.x, lane = t & 63;
  if (blockIdx.y == 0 && blockIdx.x < 4) {
    int col = blockIdx.x * 256 + t;
    w2at[col] = make_float4(w2a[col], w2a[1024 + col], w2a[2048 + col], w2a[3072 + col]);
    w2bt[col] = make_float4(w2b[col], w2b[1024 + col], w2b[2048 + col], w2b[3072 + col]);
  }
  const int bb = blockIdx.x >> 4;
  const int nt = ((blockIdx.x & 15) << 2) + (t >> 6);
  const int c = lane & 15, q = lane >> 4;
  if (blockIdx.y == 0) {
    float v[8];
#pragma unroll
    for (int j = 0; j < 8; ++j) {
      int l = q * 8 + j;
      v[j] = (l < LL) ? G2a[(size_t)(bb * LL + l) * D + nt * 16 + c] : 0.f;
    }
    bf16x8 hi, lo;
    split8(v, hi, lo);
    bf16x8* o = (bf16x8*)(G2aF + ((size_t)(bb * 64 + nt) * 2) * 512 + lane * 8);
    o[0] = hi;
    o[64] = lo;
  } else {
#pragma unroll
    for (int kc = 0; kc < 2; ++kc) {
      float v[8];
#pragma unroll
      for (int j = 0; j < 8; ++j) {
        int r = kc * 32 + q * 8 + j;
        v[j] = (r < RR) ? G1b[(size_t)(bb * RR + r) * D + nt * 16 + c] : 0.f;
      }
      bf16x8 hi, lo;
      split8(v, hi, lo);
      bf16x8* o = (bf16x8*)(G1bF + (((size_t)(bb * 64 + nt) * 2 + kc) * 2) * 512 + lane * 8);
      o[0] = hi;
      o[64] = lo;
    }
  }
}

// ---- split-bf16 MFMA GEMM core: each wave 4x4 16-tiles, direct frag loads ----
__device__ __forceinline__ void gemm4_body(const bf16x8* __restrict__ Af,
                                           const bf16x8* __restrict__ Bf,
                                           float* __restrict__ C,
                                           int M, int N, float scale,
                                           int Mtiles, int Ntiles) {
  const int lane = threadIdx.x & 63;
  const int w = threadIdx.x >> 6;
  const int mb = blockIdx.y * 8 + (w >> 1) * 4;
  const int nb = blockIdx.x * 8 + (w & 1) * 4;
  size_t ab[4], bb[4];
#pragma unroll
  for (int i = 0; i < 4; ++i) {
    int tm = mb + i; if (tm > Mtiles - 1) tm = Mtiles - 1;
    ab[i] = (size_t)tm * 4096 + lane;
    int tn = nb + i; if (tn > Ntiles - 1) tn = Ntiles - 1;
    bb[i] = (size_t)tn * 4096 + lane;
  }
  f32x4 acc[4][4];
#pragma unroll
  for (int i = 0; i < 4; ++i)
#pragma unroll
    for (int j = 0; j < 4; ++j) acc[i][j] = (f32x4){0.f, 0.f, 0.f, 0.f};
#pragma unroll 1
  for (int kc = 0; kc < 32; ++kc) {
    bf16x8 ah[4], al[4], bh[4], bl[4];
#pragma unroll
    for (int i = 0; i < 4; ++i) { ah[i] = Af[ab[i]]; al[i] = Af[ab[i] + 64]; ab[i] += 128; }
#pragma unroll
    for (int j = 0; j < 4; ++j) { bh[j] = Bf[bb[j]]; bl[j] = Bf[bb[j] + 64]; bb[j] += 128; }
#pragma unroll
    for (int i = 0; i < 4; ++i)
#pragma unroll
      for (int j = 0; j < 4; ++j) {
        acc[i][j] = MFMA16(ah[i], bh[j], acc[i][j]);
        acc[i][j] = MFMA16(al[i], bh[j], acc[i][j]);
        acc[i][j] = MFMA16(ah[i], bl[j], acc[i][j]);
      }
  }
  const int c16 = lane & 15, q = lane >> 4;
#pragma unroll
  for (int i = 0; i < 4; ++i) {
#pragma unroll
    for (int reg = 0; reg < 4; ++reg) {
      int r = (mb + i) * 16 + q * 4 + reg;
      if (r < M) {
#pragma unroll
        for (int j = 0; j < 4; ++j) {
          int col = (nb + j) * 16 + c16;
          if (col < N) C[(size_t)r * N + col] = acc[i][j][reg] * scale;
        }
      }
    }
  }
}

// 4 projection GEMMs in one launch. grid (8, 14, 4)
__global__ __launch_bounds__(256) void proj_fused(
    const bf16x8* __restrict__ v1f, const bf16x8* __restrict__ v2f,
    const bf16x8* __restrict__ wimgf, const bf16x8* __restrict__ wtxtf,
    const bf16x8* __restrict__ w1af, const bf16x8* __restrict__ w1bf,
    float* k1, float* k2, float* G2a, float* G1b) {
  const int z = blockIdx.z;
  const bf16x8* Af = (z == 0 || z == 3) ? v1f : v2f;
  const bf16x8* Bf = (z == 0) ? wimgf : (z == 1) ? wtxtf : (z == 2) ? w1af : w1bf;
  float* C = (z == 0) ? k1 : (z == 1) ? k2 : (z == 2) ? G2a : G1b;
  const int M = (z == 0 || z == 3) ? 1728 : 1440;
  const int Mt = (z == 0 || z == 3) ? 108 : 92;
  if ((int)blockIdx.y * 8 >= Mt) return;
  gemm4_body(Af, Bf, C, M, 1024, 1.f, Mt, 64);
}

// 2 cross GEMMs in one launch. grid (14, 12, 2)
__global__ __launch_bounds__(256) void cross_fused(
    const bf16x8* __restrict__ k2f, const bf16x8* __restrict__ k1f,
    const bf16x8* __restrict__ v2f, const bf16x8* __restrict__ v1f,
    float* Sbuf, float* Cbuf) {
  if (blockIdx.z == 0) gemm4_body(k2f, k1f, Sbuf, 1440, 1728, 0.03125f, 92, 108);
  else                 gemm4_body(v2f, v1f, Cbuf, 1440, 1728, 1.f, 92, 108);
}

// ---- Gram partials: grid (8, 96); y<48 -> v1 batch (36 rows), else v2 (30) ----
__global__ __launch_bounds__(256) void gram_partial(const float* __restrict__ v1,
                                                    const float* __restrict__ v2,
                                                    float* __restrict__ pg) {
  const int y = blockIdx.y, cx = blockIdx.x;
  const int isV1 = y < 48;
  const int batch = isV1 ? y : y - 48;
  const int Nr = isV1 ? RR : LL;
  const float* base = isV1 ? v1 + (size_t)batch * RR * D : v2 + (size_t)batch * LL * D;
  __shared__ __align__(16) float vs[36][132];
  const int t = threadIdx.x;
  for (int idx = t; idx < Nr * 32; idx += 256) {
    int row = idx >> 5, c4 = idx & 31;
    *(float4*)&vs[row][c4 * 4] = *(const float4*)&base[(size_t)row * D + cx * 128 + c4 * 4];
  }
  __syncthreads();
  const int nt3 = Nr / 3;                 // 12 or 10
  float acc[3][3] = {{0.f,0.f,0.f},{0.f,0.f,0.f},{0.f,0.f,0.f}};
  const int i0 = (t / nt3) * 3, j0 = (t - (t / nt3) * nt3) * 3;
  if (t < nt3 * nt3) {
    for (int k4 = 0; k4 < 32; ++k4) {
      float4 a[3], b[3];
#pragma unroll
      for (int ii = 0; ii < 3; ++ii) a[ii] = *(const float4*)&vs[i0 + ii][k4 * 4];
#pragma unroll
      for (int jj = 0; jj < 3; ++jj) b[jj] = *(const float4*)&vs[j0 + jj][k4 * 4];
#pragma unroll
      for (int ii = 0; ii < 3; ++ii)
#pragma unroll
        for (int jj = 0; jj < 3; ++jj) {
          acc[ii][jj] = fmaf(a[ii].x, b[jj].x, acc[ii][jj]);
          acc[ii][jj] = fmaf(a[ii].y, b[jj].y, acc[ii][jj]);
          acc[ii][jj] = fmaf(a[ii].z, b[jj].z, acc[ii][jj]);
          acc[ii][jj] = fmaf(a[ii].w, b[jj].w, acc[ii][jj]);
        }
    }
    float* o = pg + ((size_t)y * 8 + cx) * 1296;
#pragma unroll
    for (int ii = 0; ii < 3; ++ii)
#pragma unroll
      for (int jj = 0; jj < 3; ++jj) o[(i0 + ii) * Nr + (j0 + jj)] = acc[ii][jj];
  }
}

__global__ __launch_bounds__(256) void gram_reduce(const float* __restrict__ pg,
                                                   float* __restrict__ g11,
                                                   float* __restrict__ g22) {
  const int y = blockIdx.x;
  const int isV1 = y < 48;
  const int batch = isV1 ? y : y - 48;
  const int NN = isV1 ? RR * RR : LL * LL;
  const float* p = pg + (size_t)y * 8 * 1296;
  float* o = isV1 ? g11 + (size_t)batch * RR * RR : g22 + (size_t)batch * LL * LL;
  for (int i = threadIdx.x; i < NN; i += 256) {
    float s = 0.f;
#pragma unroll
    for (int c = 0; c < 8; ++c) s += p[c * 1296 + i];
    o[i] = s;
  }
}

// ---------------- per-(pair,direction) kernel: grid (2304, 2) x 128 ----------------
// y==0: direction A -> u2 (30), n1.   y==1: direction B -> u1 (36), n2.
__global__ __launch_bounds__(128) void pair_dir(
    const float* __restrict__ Sb,
    const bf16x8* __restrict__ G2aF, const bf16x8* __restrict__ G1bF,
    const float* __restrict__ g22, const float* __restrict__ g11,
    const float* __restrict__ b1a, const float4* __restrict__ w2at, const float* __restrict__ b2a,
    const float* __restrict__ b1b, const float4* __restrict__ w2bt, const float* __restrict__ b2b,
    float* __restrict__ U1buf, float* __restrict__ U2buf,
    float* __restrict__ N1buf, float* __restrict__ N2buf) {
  const int pair = blockIdx.x;
  const int a = pair / NB2;
  const int b = pair - a * NB2;
  const int t = threadIdx.x, lane = t & 63, w = t >> 6;  // w in {0,1}
  const int c16 = lane & 15, q = lane >> 4;

  union SM {
    struct {
      float p2s[48][36];
      float red[2][48][4];
      float sa[RR][NH];
      float qa[RR];
      float u2[LL];
      float rb[2];
    } A;
    struct {
      float p1s[32][68];
      float red[2][48][4];
      float sbm[LL][NH];
      float qb[LL];
      float u1[RR];
      float rb[2];
    } B;
  };
  __shared__ __align__(16) SM sm;

  const float* Sab = Sb + (size_t)b * LL * 1728 + (size_t)a * RR;

  if (blockIdx.y == 0) {
    // ======================= direction A =======================
    // pad-only zeroing (disjoint from S fill, same phase, no race)
    for (int i = t; i < 48 * 36; i += 128) {
      int r = i / 36, c = i - r * 36;
      if (r >= RR || c >= LL) ((float*)sm.A.p2s)[i] = 0.f;
    }
    for (int i = t; i < LL * RR; i += 128) {
      int l = i / RR, r = i - l * RR;
      sm.A.p2s[r][l] = Sab[(size_t)l * 1728 + r];
    }
    __syncthreads();
    // softmax over l per row r; 2 lanes/row (t and t^1 same wave)
    if (t < RR * 2) {
      int r = t >> 1, half = t & 1;
      float m = -1e30f;
      for (int l = half; l < LL; l += 2) m = fmaxf(m, sm.A.p2s[r][l]);
      m = fmaxf(m, __shfl_xor(m, 1));
      float s = 0.f;
      for (int l = half; l < LL; l += 2) {
        float e = __expf(sm.A.p2s[r][l] - m);
        sm.A.p2s[r][l] = e;
        s += e;
      }
      s += __shfl_xor(s, 1);
      float inv = 1.f / s;
      for (int l = half; l < LL; l += 2) sm.A.p2s[r][l] *= inv;
    }
    __syncthreads();

    // A-fragments
    bf16x8 pAh[3], pAl[3];
#pragma unroll
    for (int mt = 0; mt < 3; ++mt) {
      float v[8];
      const float* rp = &sm.A.p2s[mt * 16 + c16][q * 8];
      float4 x0 = *(const float4*)rp;
      float4 x1 = *(const float4*)(rp + 4);
      v[0] = x0.x; v[1] = x0.y; v[2] = x0.z; v[3] = x0.w;
      v[4] = x1.x; v[5] = x1.y; v[6] = x1.z; v[7] = x1.w;
      split8(v, pAh[mt], pAl[mt]);
    }

    f32x2 sc01[3][4], sc23[3][4];
#pragma unroll
    for (int mt = 0; mt < 3; ++mt)
#pragma unroll
      for (int reg = 0; reg < 4; ++reg) {
        sc01[mt][reg] = (f32x2){0.f, 0.f};
        sc23[mt][reg] = (f32x2){0.f, 0.f};
      }

    const bf16x8* gA = G2aF + ((size_t)(b * 64 + w) * 2) * 64 + lane;
#pragma unroll 2
    for (int it = 0; it < 32; ++it) {
      const bf16x8* gp = gA + (size_t)it * 256;
      bf16x8 Bh = gp[0], Bl = gp[64];
      const int col = (w + it * 2) * 16 + c16;
      float4 wv = w2at[col];
      float bias = b1a[col];
      f32x2 w01 = {wv.x, wv.y}, w23 = {wv.z, wv.w};
#pragma unroll
      for (int mt = 0; mt < 3; ++mt) {
        f32x4 acc = {bias, bias, bias, bias};
        acc = MFMA16(pAh[mt], Bh, acc);
        acc = MFMA16(pAl[mt], Bh, acc);
        acc = MFMA16(pAh[mt], Bl, acc);
#pragma unroll
        for (int reg = 0; reg < 4; ++reg) {
          float hv = fmaxf(acc[reg], 0.f);
          f32x2 hv2 = {hv, hv};
          sc01[mt][reg] += hv2 * w01;
          sc23[mt][reg] += hv2 * w23;
        }
      }
    }
#pragma unroll
    for (int mt = 0; mt < 3; ++mt)
#pragma unroll
      for (int reg = 0; reg < 4; ++reg) {
        f32x2 v01 = sc01[mt][reg], v23 = sc23[mt][reg];
#pragma unroll
        for (int m = 1; m <= 8; m <<= 1) {
          v01 += shflx2(v01, m);
          v23 += shflx2(v23, m);
        }
        if (c16 == 0) {
          f32x2* rp = (f32x2*)&sm.A.red[w][mt * 16 + q * 4 + reg][0];
          rp[0] = v01;
          rp[1] = v23;
        }
      }
    __syncthreads();
    for (int i = t; i < RR * NH; i += 128) {
      int r = i >> 2, h = i & 3;
      sm.A.sa[r][h] = sm.A.red[0][r][h] + sm.A.red[1][r][h] + b2a[h];
    }
    __syncthreads();
    // head softmax over r (36) per head: 16 lanes/head on wave 0
    if (t < 64) {
      const int h = t >> 4, i = t & 15;
      float x0 = sm.A.sa[i][h];
      float x1 = sm.A.sa[i + 16][h];
      float x2 = (i < 4) ? sm.A.sa[i + 32][h] : -1e30f;
      float m = fmaxf(fmaxf(x0, x1), x2);
      m = fmaxf(m, __shfl_xor(m, 1));
      m = fmaxf(m, __shfl_xor(m, 2));
      m = fmaxf(m, __shfl_xor(m, 4));
      m = fmaxf(m, __shfl_xor(m, 8));
      float e0 = __expf(x0 - m), e1 = __expf(x1 - m);
      float e2 = (i < 4) ? __expf(x2 - m) : 0.f;
      float s = e0 + e1 + e2;
      s += __shfl_xor(s, 1);
      s += __shfl_xor(s, 2);
      s += __shfl_xor(s, 4);
      s += __shfl_xor(s, 8);
      float inv = 1.f / s;
      sm.A.sa[i][h] = e0 * inv;
      sm.A.sa[i + 16][h] = e1 * inv;
      if (i < 4) sm.A.sa[i + 32][h] = e2 * inv;
    }
    __syncthreads();
    if (t < RR)
      sm.A.qa[t] = 0.25f * (sm.A.sa[t][0] + sm.A.sa[t][1] + sm.A.sa[t][2] + sm.A.sa[t][3]);
    __syncthreads();
    // u2[l] = sum_r qa[r] * p2[r][l]; 2 lanes per l
    if (t < LL * 2) {
      int l = t >> 1, half = t & 1;
      float x = 0.f;
      for (int r = half; r < RR; r += 2) x = fmaf(sm.A.qa[r], sm.A.p2s[r][l], x);
      x += __shfl_xor(x, 1);
      if (half == 0) {
        sm.A.u2[l] = x;
        U2buf[pair * 32 + l] = x;
      }
    }
    __syncthreads();
    // n1 = u2^T G22 u2
    float pn1 = 0.f;
    const float* G22 = g22 + (size_t)b * LL * LL;
    for (int i = t; i < LL * LL; i += 128) {
      int l = i / LL, l2 = i - l * LL;
      pn1 = fmaf(sm.A.u2[l] * sm.A.u2[l2], G22[i], pn1);
    }
#pragma unroll
    for (int off = 32; off; off >>= 1) pn1 += __shfl_down(pn1, off);
    if (lane == 0) sm.A.rb[w] = pn1;
    __syncthreads();
    if (t == 0) N1buf[pair] = sm.A.rb[0] + sm.A.rb[1];
  } else {
    // ======================= direction B =======================
    for (int i = t; i < 32 * 68; i += 128) {
      int l = i / 68, c = i - l * 68;
      if (l >= LL || c >= RR) ((float*)sm.B.p1s)[i] = 0.f;
    }
    for (int i = t; i < LL * RR; i += 128) {
      int l = i / RR, r = i - l * RR;
      sm.B.p1s[l][r] = Sab[(size_t)l * 1728 + r];
    }
    __syncthreads();
    // softmax over r per row l; 2 lanes/row
    if (t < LL * 2) {
      int l = t >> 1, half = t & 1;
      float m = -1e30f;
      for (int r = half; r < RR; r += 2) m = fmaxf(m, sm.B.p1s[l][r]);
      m = fmaxf(m, __shfl_xor(m, 1));
      float s = 0.f;
      for (int r = half; r < RR; r += 2) {
        float e = __expf(sm.B.p1s[l][r] - m);
        sm.B.p1s[l][r] = e;
        s += e;
      }
      s += __shfl_xor(s, 1);
      float inv = 1.f / s;
      for (int r = half; r < RR; r += 2) sm.B.p1s[l][r] *= inv;
    }
    __syncthreads();

    bf16x8 pBh[2][2], pBl[2][2];
#pragma unroll
    for (int mt = 0; mt < 2; ++mt)
#pragma unroll
      for (int kc = 0; kc < 2; ++kc) {
        float v[8];
        const float* rp = &sm.B.p1s[mt * 16 + c16][kc * 32 + q * 8];
        float4 x0 = *(const float4*)rp;
        float4 x1 = *(const float4*)(rp + 4);
        v[0] = x0.x; v[1] = x0.y; v[2] = x0.z; v[3] = x0.w;
        v[4] = x1.x; v[5] = x1.y; v[6] = x1.z; v[7] = x1.w;
        split8(v, pBh[mt][kc], pBl[mt][kc]);
      }

    f32x2 sc01[2][4], sc23[2][4];
#pragma unroll
    for (int mt = 0; mt < 2; ++mt)
#pragma unroll
      for (int reg = 0; reg < 4; ++reg) {
        sc01[mt][reg] = (f32x2){0.f, 0.f};
        sc23[mt][reg] = (f32x2){0.f, 0.f};
      }

    const bf16x8* gB = G1bF + ((size_t)(a * 64 + w) * 4) * 64 + lane;
#pragma unroll 2
    for (int it = 0; it < 32; ++it) {
      const bf16x8* gp = gB + (size_t)it * 512;
      bf16x8 B0h = gp[0], B0l = gp[64], B1h = gp[128], B1l = gp[192];
      const int col = (w + it * 2) * 16 + c16;
      float4 wv = w2bt[col];
      float bias = b1b[col];
      f32x2 w01 = {wv.x, wv.y}, w23 = {wv.z, wv.w};
#pragma unroll
      for (int mt = 0; mt < 2; ++mt) {
        f32x4 acc = {bias, bias, bias, bias};
        acc = MFMA16(pBh[mt][0], B0h, acc);
        acc = MFMA16(pBl[mt][0], B0h, acc);
        acc = MFMA16(pBh[mt][0], B0l, acc);
        acc = MFMA16(pBh[mt][1], B1h, acc);
        acc = MFMA16(pBl[mt][1], B1h, acc);
        acc = MFMA16(pBh[mt][1], B1l, acc);
#pragma unroll
        for (int reg = 0; reg < 4; ++reg) {
          float hv = fmaxf(acc[reg], 0.f);
          f32x2 hv2 = {hv, hv};
          sc01[mt][reg] += hv2 * w01;
          sc23[mt][reg] += hv2 * w23;
        }
      }
    }
#pragma unroll
    for (int mt = 0; mt < 2; ++mt)
#pragma unroll
      for (int reg = 0; reg < 4; ++reg) {
        f32x2 v01 = sc01[mt][reg], v23 = sc23[mt][reg];
#pragma unroll
        for (int m = 1; m <= 8; m <<= 1) {
          v01 += shflx2(v01, m);
          v23 += shflx2(v23, m);
        }
        if (c16 == 0) {
          f32x2* rp = (f32x2*)&sm.B.red[w][mt * 16 + q * 4 + reg][0];
          rp[0] = v01;
          rp[1] = v23;
        }
      }
    __syncthreads();
    for (int i = t; i < LL * NH; i += 128) {
      int l = i >> 2, h = i & 3;
      sm.B.sbm[l][h] = sm.B.red[0][l][h] + sm.B.red[1][l][h] + b2b[h];
    }
    __syncthreads();
    if (t < 64) {
      const int h = t >> 4, i = t & 15;
      float x0 = sm.B.sbm[i][h];
      float x1 = (i < 14) ? sm.B.sbm[i + 16][h] : -1e30f;
      float m = fmaxf(x0, x1);
      m = fmaxf(m, __shfl_xor(m, 1));
      m = fmaxf(m, __shfl_xor(m, 2));
      m = fmaxf(m, __shfl_xor(m, 4));
      m = fmaxf(m, __shfl_xor(m, 8));
      float e0 = __expf(x0 - m);
      float e1 = (i < 14) ? __expf(x1 - m) : 0.f;
      float s = e0 + e1;
      s += __shfl_xor(s, 1);
      s += __shfl_xor(s, 2);
      s += __shfl_xor(s, 4);
      s += __shfl_xor(s, 8);
      float inv = 1.f / s;
      sm.B.sbm[i][h] = e0 * inv;
      if (i < 14) sm.B.sbm[i + 16][h] = e1 * inv;
    }
    __syncthreads();
    if (t < LL)
      sm.B.qb[t] = 0.25f * (sm.B.sbm[t][0] + sm.B.sbm[t][1] + sm.B.sbm[t][2] + sm.B.sbm[t][3]);
    __syncthreads();
    // u1[r] = sum_l qb[l] * p1[l][r]; 2 lanes per r
    if (t < RR * 2) {
      int r = t >> 1, half = t & 1;
      float x = 0.f;
      for (int l = half; l < LL; l += 2) x = fmaf(sm.B.qb[l], sm.B.p1s[l][r], x);
      x += __shfl_xor(x, 1);
      if (half == 0) {
        sm.B.u1[r] = x;
        U1buf[pair * 40 + r] = x;
      }
    }
    __syncthreads();
    // n2 = u1^T G11 u1
    float pn2 = 0.f;
    const float* G11 = g11 + (size_t)a * RR * RR;
    for (int i = t; i < RR * RR; i += 128) {
      int r = i / RR, r2 = i - r * RR;
      pn2 = fmaf(sm.B.u1[r] * sm.B.u1[r2], G11[i], pn2);
    }
#pragma unroll
    for (int off = 32; off; off >>= 1) pn2 += __shfl_down(pn2, off);
    if (lane == 0) sm.B.rb[w] = pn2;
    __syncthreads();
    if (t == 0) N2buf[pair] = sm.B.rb[0] + sm.B.rb[1];
  }
}

// num = u2^T C u1 ; out = num / ((sqrt(n1)+eps)(sqrt(n2)+eps)). grid 2304 x 64
__global__ __launch_bounds__(64) void pair_final(
    const float* __restrict__ Cb, const float* __restrict__ U1buf,
    const float* __restrict__ U2buf, const float* __restrict__ N1buf,
    const float* __restrict__ N2buf, float* __restrict__ out) {
  const int pair = blockIdx.x;
  const int a = pair / NB2;
  const int b = pair - a * NB2;
  const int t = threadIdx.x;
  const float* Cab = Cb + (size_t)b * LL * 1728 + (size_t)a * RR;
  const float* u1 = U1buf + pair * 40;
  const float* u2 = U2buf + pair * 32;
  float pnum = 0.f;
  for (int i = t; i < LL * RR; i += 64) {
    int l = i / RR, r = i - l * RR;
    pnum = fmaf(u2[l] * u1[r], Cab[(size_t)l * 1728 + r], pnum);
  }
#pragma unroll
  for (int off = 32; off; off >>= 1) pnum += __shfl_down(pnum, off);
  if (t == 0) {
    float n1 = sqrtf(fmaxf(N1buf[pair], 0.f));
    float n2 = sqrtf(fmaxf(N2buf[pair], 0.f));
    out[pair] = pnum / ((n1 + 1e-8f) * (n2 + 1e-8f));
  }
}

extern "C" void kernel_launch(void* const* d_in, const int* in_sizes, int n_in,
                              void* d_out, int out_size, void* d_ws, size_t ws_size,
                              hipStream_t stream) {
  const float* v1    = (const float*)d_in[0];
  const float* v2    = (const float*)d_in[1];
  const float* w_img = (const float*)d_in[2];
  const float* w_txt = (const float*)d_in[3];
  const float* w1a   = (const float*)d_in[4];
  const float* b1a   = (const float*)d_in[5];
  const float* w2a   = (const float*)d_in[6];
  const float* b2a   = (const float*)d_in[7];
  const float* w1b   = (const float*)d_in[8];
  const float* b1b   = (const float*)d_in[9];
  const float* w2b   = (const float*)d_in[10];
  const float* b2b   = (const float*)d_in[11];
  float* out = (float*)d_out;

  // fp32 region
  float* ws   = (float*)d_ws;
  float* k1   = ws;                           // 1728*1024
  float* k2   = k1 + (size_t)1728 * 1024;     // 1440*1024
  float* G2a  = k2 + (size_t)1440 * 1024;     // 1440*1024
  float* G1b  = G2a + (size_t)1440 * 1024;    // 1728*1024
  float* Sbuf = G1b + (size_t)1728 * 1024;    // 1440*1728
  float* Cbuf = Sbuf + (size_t)1440 * 1728;   // 1440*1728
  float* g22  = Cbuf + (size_t)1440 * 1728;   // 48*900
  float* g11  = g22 + (size_t)48 * 900;       // 48*1296

  // split-bf16 fragment region
  unsigned short* fb    = (unsigned short*)(g11 + (size_t)48 * 1296);
  unsigned short* v1f   = fb;                                  // 108 tiles
  unsigned short* v2f   = v1f + (size_t)108 * 32768;           //  92 tiles
  unsigned short* k1f   = v2f + (size_t)92 * 32768;            // 108 tiles
  unsigned short* k2f   = k1f + (size_t)108 * 32768;           //  92 tiles
  unsigned short* wimgf = k2f + (size_t)92 * 32768;            //  64 tiles each
  unsigned short* wtxtf = wimgf + (size_t)64 * 32768;
  unsigned short* w1af  = wtxtf + (size_t)64 * 32768;
  unsigned short* w1bf  = w1af + (size_t)64 * 32768;
  unsigned short* G2aF  = w1bf + (size_t)64 * 32768;           // 48 * 65536 ush
  unsigned short* G1bF  = G2aF + (size_t)48 * 65536;           // 48 * 131072 ush

  // gram partial buffer ALIASES k1f (4 MB <= 6.9 MB): gram_reduce completes
  // before conv_k writes k1f (stream-ordered), so no conflict.
  float* pg = (float*)k1f;

  // w2 transposed (float4 per col) ALIASES k1 fp32 (dead after conv_k reads it;
  // written by convG which runs after conv_k).
  float4* w2at = (float4*)k1;                 // 1024 float4
  float4* w2bt = w2at + 1024;                 // 1024 float4

  // u-vector / norm buffers ALIAS G2a fp32 (dead after convG reads it;
  // written by pair_dir which runs after cross_fused).
  float* U2buf = G2a;                         // 2304*32
  float* U1buf = U2buf + (size_t)2304 * 32;   // 2304*40
  float* N1buf = U1buf + (size_t)2304 * 40;   // 2304
  float* N2buf = N1buf + 2304;                // 2304

  conv6<<<dim3(864, 6), 256, 0, stream>>>(v1, v2, w_img, w_txt, w1a, w1b,
                                          v1f, v2f, wimgf, wtxtf, w1af, w1bf);
  gram_partial<<<dim3(8, 96), 256, 0, stream>>>(v1, v2, pg);
  gram_reduce<<<96, 256, 0, stream>>>(pg, g11, g22);

  proj_fused<<<dim3(8, 14, 4), 256, 0, stream>>>(
      (const bf16x8*)v1f, (const bf16x8*)v2f, (const bf16x8*)wimgf,
      (const bf16x8*)wtxtf, (const bf16x8*)w1af, (const bf16x8*)w1bf,
      k1, k2, G2a, G1b);

  conv_k<<<dim3(864, 2), 256, 0, stream>>>(k1, k2, k1f, k2f);
  convG<<<dim3(768, 2), 256, 0, stream>>>(G2a, G1b, w2a, w2b, G2aF, G1bF, w2at, w2bt);

  cross_fused<<<dim3(14, 12, 2), 256, 0, stream>>>(
      (const bf16x8*)k2f, (const bf16x8*)k1f, (const bf16x8*)v2f, (const bf16x8*)v1f,
      Sbuf, Cbuf);

  pair_dir<<<dim3(2304, 2), 128, 0, stream>>>(
      Sbuf, (const bf16x8*)G2aF, (const bf16x8*)G1bF, g22, g11,
      b1a, w2at, b2a, b1b, w2bt, b2b, U1buf, U2buf, N1buf, N2buf);
  pair_final<<<2304, 64, 0, stream>>>(Cbuf, U1buf, U2buf, N1buf, N2buf, out);
}